// Round 1
// baseline (2738.450 us; speedup 1.0000x reference)
//
#include <hip/hip_runtime.h>
#include <math.h>
#include <stdint.h>

#define NN 50000
#define NE 300000
#define NT 4
#define DD 256
#define RR 768
#define NG 128
#define NSTEP 8
#define MPAD 50048  // 391*128

#define BM 128
#define BN 128
#define BK 64

typedef __attribute__((ext_vector_type(8))) short bf16x8;
typedef __attribute__((ext_vector_type(4))) float f32x4;
typedef unsigned short u16;
typedef unsigned int u32;

__device__ __forceinline__ float b2f(u16 u) {
  union { u32 i; float f; } c; c.i = ((u32)u) << 16; return c.f;
}
__device__ __forceinline__ u16 f2b(float f) {
  union { float f; u32 i; } c; c.f = f;
  u32 x = c.i;
  u32 r = (x + 0x7fffu + ((x >> 16) & 1u)) >> 16;
  return (u16)r;
}

__device__ __forceinline__ void load_lds16(const void* g, void* l) {
  __builtin_amdgcn_global_load_lds((const __attribute__((address_space(1))) u32*)g,
                                   (__attribute__((address_space(3))) u32*)l, 16, 0, 0);
}

// ---- weight prep: Wt_e[c][k] = W_e[c>>8][k][c&255], c in [0,1024) ----
__global__ void k_conv_we(const float* __restrict__ W_e, u16* __restrict__ Wt) {
  int i = blockIdx.x * 256 + threadIdx.x;  // 1024*256
  int c = i >> 8, d = i & 255;
  Wt[c * 256 + d] = f2b(W_e[(c >> 8) * 65536 + d * 256 + (c & 255)]);
}
// W: [256][N] row-major -> Wt[n][k] = W[k][n]
__global__ void k_conv_w(const float* __restrict__ W, u16* __restrict__ Wt, int N) {
  int i = blockIdx.x * 256 + threadIdx.x;  // N*256
  int n = i >> 8, k = i & 255;
  Wt[n * 256 + k] = f2b(W[k * N + n]);
}

__global__ void k_init_h(const float* __restrict__ feat, float* __restrict__ h, u16* __restrict__ hb) {
  int i = blockIdx.x * 256 + threadIdx.x;  // MPAD*256
  int n = i >> 8, d = i & 255;
  float v = (n < NN) ? feat[(size_t)n * 1024 + d] : 0.f;
  h[i] = v;
  hb[i] = f2b(v);
}

__global__ void k_hist(const int* __restrict__ dst, int* __restrict__ deg) {
  int e = blockIdx.x * 256 + threadIdx.x;
  if (e < NE) atomicAdd(&deg[dst[e]], 1);
}

__global__ void k_scan(const int* __restrict__ deg, int* __restrict__ rp) {
  __shared__ int sh[1024];
  __shared__ int carry;
  int t = threadIdx.x;
  if (t == 0) carry = 0;
  __syncthreads();
  for (int base = 0; base < NN; base += 1024) {
    int i = base + t;
    int v = (i < NN) ? deg[i] : 0;
    sh[t] = v;
    __syncthreads();
    for (int off = 1; off < 1024; off <<= 1) {
      int tmp = (t >= off) ? sh[t - off] : 0;
      __syncthreads();
      sh[t] += tmp;
      __syncthreads();
    }
    if (i < NN) rp[i] = carry + sh[t] - v;
    __syncthreads();
    if (t == 0) carry += sh[1023];
    __syncthreads();
  }
  if (t == 0) rp[NN] = carry;
}

__global__ void k_scatter(const int* __restrict__ src, const int* __restrict__ dst,
                          const int* __restrict__ ety, const int* __restrict__ rp,
                          int* __restrict__ cursor, int* __restrict__ goff) {
  int e = blockIdx.x * 256 + threadIdx.x;
  if (e < NE) {
    int d = dst[e];
    int p = rp[d] + atomicAdd(&cursor[d], 1);
    goff[p] = src[e] * 1024 + ety[e] * 256;
  }
}

// ---- GEMM: C[MPAD][N] = A[MPAD][256](bf16) * Bt[N][256]^T(bf16) + bias[N] ----
template <int OUTBF16>
__global__ __launch_bounds__(256, 2) void k_gemm(const u16* __restrict__ A, const u16* __restrict__ Bt,
                                                 const float* __restrict__ bias, void* __restrict__ Cout,
                                                 int N) {
  const int K = 256;
  __shared__ __align__(16) char lds[(BM + BN) * BK * 2];
  char* As = lds;
  char* Bs = lds + BM * BK * 2;
  const int tid = threadIdx.x;
  const int w = tid >> 6, l = tid & 63;
  const int m0 = blockIdx.y * BM, n0 = blockIdx.x * BN;
  const int rld = tid >> 3;  // 0..31
  const int cld = tid & 7;
  const int wm = (w >> 1) * 64, wn = (w & 1) * 64;
  const int fr = l & 15, kq = l >> 4;
  f32x4 acc[4][4];
#pragma unroll
  for (int m = 0; m < 4; ++m)
#pragma unroll
    for (int n = 0; n < 4; ++n) acc[m][n] = (f32x4){0.f, 0.f, 0.f, 0.f};

  for (int k0 = 0; k0 < K; k0 += BK) {
#pragma unroll
    for (int p = 0; p < 4; ++p) {
      int row = p * 32 + rld;
      int ks = k0 + ((cld ^ (row & 7)) << 3);  // inverse-swizzled global source
      load_lds16(A + (size_t)(m0 + row) * K + ks, As + p * 4096 + w * 1024);
    }
#pragma unroll
    for (int p = 0; p < 4; ++p) {
      int row = p * 32 + rld;
      int ks = k0 + ((cld ^ (row & 7)) << 3);
      load_lds16(Bt + (size_t)(n0 + row) * K + ks, Bs + p * 4096 + w * 1024);
    }
    asm volatile("s_waitcnt vmcnt(0)" ::: "memory");
    __syncthreads();
#pragma unroll
    for (int kk = 0; kk < BK; kk += 32) {
      bf16x8 af[4], bfr[4];
      int kb = (kk + kq * 8) * 2;
#pragma unroll
      for (int m = 0; m < 4; ++m) {
        int R = wm + m * 16 + fr;
        af[m] = *(const bf16x8*)(As + R * 128 + (kb ^ ((R & 7) << 4)));
      }
#pragma unroll
      for (int n = 0; n < 4; ++n) {
        int R = wn + n * 16 + fr;
        bfr[n] = *(const bf16x8*)(Bs + R * 128 + (kb ^ ((R & 7) << 4)));
      }
#pragma unroll
      for (int m = 0; m < 4; ++m)
#pragma unroll
        for (int n = 0; n < 4; ++n)
          acc[m][n] = __builtin_amdgcn_mfma_f32_16x16x32_bf16(af[m], bfr[n], acc[m][n], 0, 0, 0);
    }
    __syncthreads();
  }
#pragma unroll
  for (int m = 0; m < 4; ++m) {
#pragma unroll
    for (int n = 0; n < 4; ++n) {
      int col = n0 + wn + n * 16 + fr;
      float bv = bias[col];
#pragma unroll
      for (int j = 0; j < 4; ++j) {
        int row = m0 + wm + m * 16 + kq * 4 + j;
        float v = acc[m][n][j] + bv;
        if (OUTBF16)
          ((u16*)Cout)[(size_t)row * N + col] = f2b(v);
        else
          ((float*)Cout)[(size_t)row * N + col] = v;
      }
    }
  }
}

// ---- aggregation: a[n] = sum over incoming edges of ht[goff + :256] ----
__global__ __launch_bounds__(256) void k_aggr(const u16* __restrict__ ht, const int* __restrict__ rp,
                                              const int* __restrict__ goff, u16* __restrict__ ab) {
  int w = threadIdx.x >> 6, l = threadIdx.x & 63;
  int n = blockIdx.x * 4 + w;
  if (n >= MPAD) return;
  float a0 = 0.f, a1 = 0.f, a2 = 0.f, a3 = 0.f;
  if (n < NN) {
    int s = rp[n], e = rp[n + 1];
    for (int i = s; i < e; ++i) {
      const u16* pm = ht + (size_t)goff[i] + l * 4;
      ushort4 u = *(const ushort4*)pm;
      a0 += b2f(u.x); a1 += b2f(u.y); a2 += b2f(u.z); a3 += b2f(u.w);
    }
  }
  ushort4 o;
  o.x = f2b(a0); o.y = f2b(a1); o.z = f2b(a2); o.w = f2b(a3);
  *(ushort4*)(ab + (size_t)n * 256 + l * 4) = o;
}

__device__ __forceinline__ float gru1(float irv, float izv, float inv2, float hrv, float hzv, float hnv,
                                      float hvv) {
  float r = 1.f / (1.f + expf(-(irv + hrv)));
  float z = 1.f / (1.f + expf(-(izv + hzv)));
  float ng = tanhf(inv2 + r * hnv);
  return (1.f - z) * ng + z * hvv;
}

__global__ __launch_bounds__(256) void k_gru(const float* __restrict__ gi, const float* __restrict__ gh,
                                             float* __restrict__ h, u16* __restrict__ hb) {
  int i = blockIdx.x * 256 + threadIdx.x;  // MPAD*64
  int n = i >> 6, q = (i & 63) << 2;
  const float* gin = gi + (size_t)n * 768 + q;
  const float* ghn = gh + (size_t)n * 768 + q;
  float4 o;
  if (n < NN) {
    float4 hv = *(const float4*)(h + (size_t)n * 256 + q);
    float4 ir = *(const float4*)(gin);
    float4 iz = *(const float4*)(gin + 256);
    float4 inn = *(const float4*)(gin + 512);
    float4 hr = *(const float4*)(ghn);
    float4 hz = *(const float4*)(ghn + 256);
    float4 hn = *(const float4*)(ghn + 512);
    o.x = gru1(ir.x, iz.x, inn.x, hr.x, hz.x, hn.x, hv.x);
    o.y = gru1(ir.y, iz.y, inn.y, hr.y, hz.y, hn.y, hv.y);
    o.z = gru1(ir.z, iz.z, inn.z, hr.z, hz.z, hn.z, hv.z);
    o.w = gru1(ir.w, iz.w, inn.w, hr.w, hz.w, hn.w, hv.w);
  } else {
    o.x = o.y = o.z = o.w = 0.f;
  }
  *(float4*)(h + (size_t)n * 256 + q) = o;
  ushort4 ob;
  ob.x = f2b(o.x); ob.y = f2b(o.y); ob.z = f2b(o.z); ob.w = f2b(o.w);
  *(ushort4*)(hb + (size_t)n * 256 + q) = ob;
}

__global__ __launch_bounds__(256) void k_pool(const float* __restrict__ h, const float* __restrict__ feat,
                                              const int* __restrict__ n2g, float* __restrict__ pooled) {
  __shared__ int sg[256];
  int base = blockIdx.x * 256;
  int t = threadIdx.x;
  int nmax = NN - base;
  if (nmax > 256) nmax = 256;
  if (t < nmax) sg[t] = n2g[base + t];
  __syncthreads();
  int c = t << 2;
  float a0 = 0.f, a1 = 0.f, a2 = 0.f, a3 = 0.f;
  int cur = sg[0];
  for (int k = 0; k < nmax; ++k) {
    int g = sg[k];
    if (g != cur) {
      atomicAdd(&pooled[cur * 1024 + c], a0);
      atomicAdd(&pooled[cur * 1024 + c + 1], a1);
      atomicAdd(&pooled[cur * 1024 + c + 2], a2);
      atomicAdd(&pooled[cur * 1024 + c + 3], a3);
      a0 = a1 = a2 = a3 = 0.f;
      cur = g;
    }
    int n = base + k;
    float4 v = (c < 256) ? *(const float4*)(h + (size_t)n * 256 + c)
                         : *(const float4*)(feat + (size_t)n * 1024 + c);
    a0 += v.x; a1 += v.y; a2 += v.z; a3 += v.w;
  }
  atomicAdd(&pooled[cur * 1024 + c], a0);
  atomicAdd(&pooled[cur * 1024 + c + 1], a1);
  atomicAdd(&pooled[cur * 1024 + c + 2], a2);
  atomicAdd(&pooled[cur * 1024 + c + 3], a3);
}

__global__ void k_cnt(const int* __restrict__ n2g, int* __restrict__ cnt) {
  int n = blockIdx.x * 256 + threadIdx.x;
  if (n < NN) atomicAdd(&cnt[n2g[n]], 1);
}

__global__ __launch_bounds__(256) void k_head(const float* __restrict__ pooled, const int* __restrict__ cnt,
                                              const float* __restrict__ W1, const float* __restrict__ b1,
                                              const float* __restrict__ W2, const float* __restrict__ b2,
                                              float* __restrict__ out) {
  __shared__ float sp[1024];
  __shared__ float red[256];
  int g = blockIdx.x, t = threadIdx.x;
  float inv = 1.f / fmaxf((float)cnt[g], 1.f);
  for (int i = t; i < 1024; i += 256) sp[i] = pooled[g * 1024 + i] * inv;
  __syncthreads();
  float acc = b1[t];
  for (int k = 0; k < 1024; ++k) acc += sp[k] * W1[k * 256 + t];
  float hc = fmaxf(acc, 0.f);
  red[t] = hc * W2[t];
  __syncthreads();
  for (int s2 = 128; s2 > 0; s2 >>= 1) {
    if (t < s2) red[t] += red[t + s2];
    __syncthreads();
  }
  if (t == 0) out[g] = 1.f / (1.f + expf(-(red[0] + b2[0])));
}

extern "C" void kernel_launch(void* const* d_in, const int* in_sizes, int n_in, void* d_out, int out_size,
                              void* d_ws, size_t ws_size, hipStream_t stream) {
  const float* feat = (const float*)d_in[0];
  const float* W_e = (const float*)d_in[1];
  const float* b_e = (const float*)d_in[2];
  const float* W_ih = (const float*)d_in[3];
  const float* W_hh = (const float*)d_in[4];
  const float* b_ih = (const float*)d_in[5];
  const float* b_hh = (const float*)d_in[6];
  const float* W1 = (const float*)d_in[7];
  const float* b1 = (const float*)d_in[8];
  const float* W2 = (const float*)d_in[9];
  const float* b2 = (const float*)d_in[10];
  const int* src = (const int*)d_in[11];
  const int* dst = (const int*)d_in[12];
  const int* ety = (const int*)d_in[13];
  const int* n2g = (const int*)d_in[14];

  char* p = (char*)d_ws;
  auto alloc = [&](size_t b) { char* r = p; p += (b + 255) & ~(size_t)255; return r; };
  float* h = (float*)alloc((size_t)MPAD * 256 * 4);
  u16* hb = (u16*)alloc((size_t)MPAD * 256 * 2);
  u16* ab = (u16*)alloc((size_t)MPAD * 256 * 2);
  u16* ht = (u16*)alloc((size_t)MPAD * 1024 * 2);
  float* gi = (float*)alloc((size_t)MPAD * 768 * 4);
  float* gh = (float*)alloc((size_t)MPAD * 768 * 4);
  u16* Wt_e = (u16*)alloc(1024 * 256 * 2);
  u16* Wt_ih = (u16*)alloc(768 * 256 * 2);
  u16* Wt_hh = (u16*)alloc(768 * 256 * 2);
  int* deg = (int*)alloc((size_t)NN * 4);
  int* rp = (int*)alloc((size_t)(NN + 1) * 4);
  int* cursor = (int*)alloc((size_t)NN * 4);
  int* goff = (int*)alloc((size_t)NE * 4);
  float* pooled = (float*)alloc((size_t)NG * 1024 * 4);
  int* cnt = (int*)alloc((size_t)NG * 4);

  hipMemsetAsync(deg, 0, (size_t)NN * 4, stream);
  hipMemsetAsync(cursor, 0, (size_t)NN * 4, stream);
  hipMemsetAsync(pooled, 0, (size_t)NG * 1024 * 4, stream);
  hipMemsetAsync(cnt, 0, (size_t)NG * 4, stream);

  k_conv_we<<<1024, 256, 0, stream>>>(W_e, Wt_e);
  k_conv_w<<<768, 256, 0, stream>>>(W_ih, Wt_ih, 768);
  k_conv_w<<<768, 256, 0, stream>>>(W_hh, Wt_hh, 768);
  k_init_h<<<MPAD, 256, 0, stream>>>(feat, h, hb);
  k_hist<<<(NE + 255) / 256, 256, 0, stream>>>(dst, deg);
  k_scan<<<1, 1024, 0, stream>>>(deg, rp);
  k_scatter<<<(NE + 255) / 256, 256, 0, stream>>>(src, dst, ety, rp, cursor, goff);

  for (int step = 0; step < NSTEP; ++step) {
    k_gemm<1><<<dim3(1024 / BN, MPAD / BM), 256, 0, stream>>>(hb, Wt_e, b_e, (void*)ht, 1024);
    k_aggr<<<MPAD / 4, 256, 0, stream>>>(ht, rp, goff, ab);
    k_gemm<0><<<dim3(768 / BN, MPAD / BM), 256, 0, stream>>>(ab, Wt_ih, b_ih, (void*)gi, 768);
    k_gemm<0><<<dim3(768 / BN, MPAD / BM), 256, 0, stream>>>(hb, Wt_hh, b_hh, (void*)gh, 768);
    k_gru<<<MPAD / 4, 256, 0, stream>>>(gi, gh, h, hb);
  }

  k_pool<<<(NN + 255) / 256, 256, 0, stream>>>(h, feat, n2g, pooled);
  k_cnt<<<(NN + 255) / 256, 256, 0, stream>>>(n2g, cnt);
  k_head<<<NG, 256, 0, stream>>>(pooled, cnt, W1, b1, W2, b2, (float*)d_out);
}

// Round 2
// 1857.655 us; speedup vs baseline: 1.4741x; 1.4741x over previous
//
#include <hip/hip_runtime.h>
#include <math.h>
#include <stdint.h>

#define NN 50000
#define NE 300000
#define NG 128
#define NSTEP 8
#define MPAD 50048  // 391*128
#define SCB 196     // ceil(NN/256)
#define PCH 8

#define BM 128
#define BN 128
#define BK 64

typedef __attribute__((ext_vector_type(8))) short bf16x8;
typedef __attribute__((ext_vector_type(4))) float f32x4;
typedef unsigned short u16;
typedef unsigned int u32;

__device__ __forceinline__ float b2f(u16 u) {
  union { u32 i; float f; } c; c.i = ((u32)u) << 16; return c.f;
}
__device__ __forceinline__ u16 f2b(float f) {
  union { float f; u32 i; } c; c.f = f;
  u32 x = c.i;
  u32 r = (x + 0x7fffu + ((x >> 16) & 1u)) >> 16;
  return (u16)r;
}

__device__ __forceinline__ void load_lds16(const void* g, void* l) {
  __builtin_amdgcn_global_load_lds((const __attribute__((address_space(1))) u32*)g,
                                   (__attribute__((address_space(3))) u32*)l, 16, 0, 0);
}

// ---------------- weight prep ----------------
// Wt_e[c][k] = W_e[c>>8][k][c&255]
__global__ void k_conv_we(const float* __restrict__ W_e, u16* __restrict__ Wt) {
  int i = blockIdx.x * 256 + threadIdx.x;  // 1024*256
  int c = i >> 8, d = i & 255;
  Wt[c * 256 + d] = f2b(W_e[(c >> 8) * 65536 + d * 256 + (c & 255)]);
}
// RZ weights, variant AH: k<256 -> W_ih[k][n], k>=256 -> W_hh[k-256][n]   (n in [0,512))
// variant HA: k<256 -> W_hh[k][n], k>=256 -> W_ih[k-256][n]
__global__ void k_conv_rz(const float* __restrict__ W_ih, const float* __restrict__ W_hh,
                          u16* __restrict__ ah, u16* __restrict__ ha) {
  int i = blockIdx.x * 256 + threadIdx.x;  // 512*512
  int n = i >> 9, k = i & 511;
  float va = (k < 256) ? W_ih[k * 768 + n] : W_hh[(k - 256) * 768 + n];
  float vh = (k < 256) ? W_hh[k * 768 + n] : W_ih[(k - 256) * 768 + n];
  ah[n * 512 + k] = f2b(va);
  ha[n * 512 + k] = f2b(vh);
}
// n-gate weights: Wt[n][k] = W[k][512+n], n,k in [0,256)
__global__ void k_conv_n(const float* __restrict__ W, u16* __restrict__ Wt) {
  int i = blockIdx.x * 256 + threadIdx.x;  // 256*256
  int n = i >> 8, k = i & 255;
  Wt[n * 256 + k] = f2b(W[k * 768 + 512 + n]);
}
__global__ void k_brz(const float* __restrict__ b_ih, const float* __restrict__ b_hh,
                      float* __restrict__ b_rz) {
  int i = blockIdx.x * 256 + threadIdx.x;  // 512
  if (i < 512) b_rz[i] = b_ih[i] + b_hh[i];
}

// acat layout per row (768 cols): [hbA (256) | ab (256) | hbB (256)]
__global__ void k_init_h(const float* __restrict__ feat, u16* __restrict__ acat) {
  int i = blockIdx.x * 256 + threadIdx.x;  // MPAD*64
  int n = i >> 6, d = (i & 63) << 2;
  ushort4 o;
  if (n < NN) {
    float4 v = *(const float4*)(feat + (size_t)n * 1024 + d);
    o.x = f2b(v.x); o.y = f2b(v.y); o.z = f2b(v.z); o.w = f2b(v.w);
  } else {
    o.x = o.y = o.z = o.w = 0;
  }
  *(ushort4*)(acat + (size_t)n * 768 + d) = o;
}

// ---------------- CSR build ----------------
__global__ void k_hist(const int* __restrict__ dst, int* __restrict__ deg) {
  int e = blockIdx.x * 256 + threadIdx.x;
  if (e < NE) atomicAdd(&deg[dst[e]], 1);
}
__global__ void k_scan1(const int* __restrict__ deg, int* __restrict__ part, int* __restrict__ bsum) {
  __shared__ int sh[256];
  int b = blockIdx.x, t = threadIdx.x;
  int i = b * 256 + t;
  int v = (i < NN) ? deg[i] : 0;
  sh[t] = v;
  __syncthreads();
  for (int off = 1; off < 256; off <<= 1) {
    int tmp = (t >= off) ? sh[t - off] : 0;
    __syncthreads();
    sh[t] += tmp;
    __syncthreads();
  }
  if (i < NN) part[i] = sh[t] - v;
  if (t == 255) bsum[b] = sh[255];
}
__global__ void k_scan2(const int* __restrict__ bsum, int* __restrict__ boff) {
  __shared__ int sh[256];
  int t = threadIdx.x;
  int v = (t < SCB) ? bsum[t] : 0;
  sh[t] = v;
  __syncthreads();
  for (int off = 1; off < 256; off <<= 1) {
    int tmp = (t >= off) ? sh[t - off] : 0;
    __syncthreads();
    sh[t] += tmp;
    __syncthreads();
  }
  boff[t] = sh[t] - v;
  if (t == 255) boff[256] = sh[255];
}
__global__ void k_scan3(const int* __restrict__ part, const int* __restrict__ boff, int* __restrict__ rp) {
  int i = blockIdx.x * 256 + threadIdx.x;
  if (i < NN) rp[i] = part[i] + boff[i >> 8];
  if (i == NN) rp[NN] = boff[256];
}
__global__ void k_scatter(const int* __restrict__ src, const int* __restrict__ dst,
                          const int* __restrict__ ety, const int* __restrict__ rp,
                          int* __restrict__ cursor, int* __restrict__ goff) {
  int e = blockIdx.x * 256 + threadIdx.x;
  if (e < NE) {
    int d = dst[e];
    int p = rp[d] + atomicAdd(&cursor[d], 1);
    goff[p] = src[e] * 1024 + ety[e] * 256;
  }
}
__global__ void k_gstart(const int* __restrict__ n2g, int* __restrict__ gstart) {
  int n = blockIdx.x * 256 + threadIdx.x;
  if (n >= NN) return;
  int g = n2g[n];
  int gp = (n == 0) ? -1 : n2g[n - 1];
  for (int x = gp + 1; x <= g; ++x) gstart[x] = n;
  if (n == NN - 1)
    for (int x = g + 1; x <= NG; ++x) gstart[x] = NN;
}

// ---------------- GEMM: C[M][N] = A[M][K](bf16,lda) * Bt[N][K]^T + bias ----------------
// MODE 0: C = bf16(acc+bias)
// MODE 1: C = bf16(sigmoid(acc+bias))       (r,z gates)
// MODE 2: GRU final: hnew = bf16((1-z)*tanh(in + r*(acc+bias)) + z*hold)
template <int MODE>
__global__ __launch_bounds__(256, 2) void k_gemm(const u16* __restrict__ A, int lda, int K,
                                                 const u16* __restrict__ Bt,
                                                 const float* __restrict__ bias,
                                                 u16* __restrict__ C, int ldc,
                                                 const u16* __restrict__ rzb,
                                                 const u16* __restrict__ inb,
                                                 const u16* __restrict__ hold,
                                                 u16* __restrict__ hnew) {
  __shared__ __align__(16) char lds[(BM + BN) * BK * 2];
  char* As = lds;
  char* Bs = lds + BM * BK * 2;
  const int tid = threadIdx.x;
  const int w = tid >> 6, l = tid & 63;
  const int m0 = blockIdx.y * BM, n0 = blockIdx.x * BN;
  const int rld = tid >> 3;  // 0..31
  const int cld = tid & 7;
  const int wm = (w >> 1) * 64, wn = (w & 1) * 64;
  const int fr = l & 15, kq = l >> 4;
  f32x4 acc[4][4];
#pragma unroll
  for (int m = 0; m < 4; ++m)
#pragma unroll
    for (int n = 0; n < 4; ++n) acc[m][n] = (f32x4){0.f, 0.f, 0.f, 0.f};

  for (int k0 = 0; k0 < K; k0 += BK) {
#pragma unroll
    for (int p = 0; p < 4; ++p) {
      int row = p * 32 + rld;
      int ks = k0 + ((cld ^ (row & 7)) << 3);  // inverse-swizzled global source
      load_lds16(A + (size_t)(m0 + row) * lda + ks, As + p * 4096 + w * 1024);
    }
#pragma unroll
    for (int p = 0; p < 4; ++p) {
      int row = p * 32 + rld;
      int ks = k0 + ((cld ^ (row & 7)) << 3);
      load_lds16(Bt + (size_t)(n0 + row) * K + ks, Bs + p * 4096 + w * 1024);
    }
    asm volatile("s_waitcnt vmcnt(0)" ::: "memory");
    __syncthreads();
#pragma unroll
    for (int kk = 0; kk < BK; kk += 32) {
      bf16x8 af[4], bfr[4];
      int kb = (kk + kq * 8) * 2;
#pragma unroll
      for (int m = 0; m < 4; ++m) {
        int R = wm + m * 16 + fr;
        af[m] = *(const bf16x8*)(As + R * 128 + (kb ^ ((R & 7) << 4)));
      }
#pragma unroll
      for (int n = 0; n < 4; ++n) {
        int R = wn + n * 16 + fr;
        bfr[n] = *(const bf16x8*)(Bs + R * 128 + (kb ^ ((R & 7) << 4)));
      }
#pragma unroll
      for (int m = 0; m < 4; ++m)
#pragma unroll
        for (int n = 0; n < 4; ++n)
          acc[m][n] = __builtin_amdgcn_mfma_f32_16x16x32_bf16(af[m], bfr[n], acc[m][n], 0, 0, 0);
    }
    __syncthreads();
  }
#pragma unroll
  for (int m = 0; m < 4; ++m) {
#pragma unroll
    for (int n = 0; n < 4; ++n) {
      int col = n0 + wn + n * 16 + fr;
      float bv = bias[col];
#pragma unroll
      for (int j = 0; j < 4; ++j) {
        int row = m0 + wm + m * 16 + kq * 4 + j;
        float v = acc[m][n][j] + bv;
        if (MODE == 0) {
          C[(size_t)row * ldc + col] = f2b(v);
        } else if (MODE == 1) {
          C[(size_t)row * ldc + col] = f2b(1.f / (1.f + expf(-v)));
        } else {
          float r = b2f(rzb[(size_t)row * 512 + col]);
          float z = b2f(rzb[(size_t)row * 512 + 256 + col]);
          float in_ = b2f(inb[(size_t)row * 256 + col]);
          float ho = b2f(hold[(size_t)row * 768 + col]);
          float ng = tanhf(in_ + r * v);
          float hv = (1.f - z) * ng + z * ho;
          hnew[(size_t)row * 768 + col] = f2b(hv);
        }
      }
    }
  }
}

// ---- aggregation: ab[n] = sum over incoming edges of ht[goff + :256] ----
__global__ __launch_bounds__(256) void k_aggr(const u16* __restrict__ ht, const int* __restrict__ rp,
                                              const int* __restrict__ goff, u16* __restrict__ acat) {
  int w = threadIdx.x >> 6, l = threadIdx.x & 63;
  int n = blockIdx.x * 4 + w;
  if (n >= MPAD) return;
  float a0 = 0.f, a1 = 0.f, a2 = 0.f, a3 = 0.f;
  if (n < NN) {
    int s = rp[n], e = rp[n + 1];
    for (int i = s; i < e; ++i) {
      const u16* pm = ht + (size_t)goff[i] + l * 4;
      ushort4 u = *(const ushort4*)pm;
      a0 += b2f(u.x); a1 += b2f(u.y); a2 += b2f(u.z); a3 += b2f(u.w);
    }
  }
  ushort4 o;
  o.x = f2b(a0); o.y = f2b(a1); o.z = f2b(a2); o.w = f2b(a3);
  *(ushort4*)(acat + (size_t)n * 768 + 256 + l * 4) = o;
}

// ---------------- pooling ----------------
__global__ __launch_bounds__(256) void k_pool(const u16* __restrict__ hb, const float* __restrict__ feat,
                                              const int* __restrict__ gstart, float* __restrict__ pooled) {
  int g = blockIdx.x, ch = blockIdx.y, t = threadIdx.x;
  int s = gstart[g], e = gstart[g + 1];
  int tot = e - s;
  int per = (tot + PCH - 1) / PCH;
  int ns = s + ch * per;
  int ne = ns + per < e ? ns + per : e;
  if (ns >= ne) return;
  int c = t << 2;
  float a0 = 0.f, a1 = 0.f, a2 = 0.f, a3 = 0.f;
  if (c < 256) {
    for (int n = ns; n < ne; ++n) {
      ushort4 u = *(const ushort4*)(hb + (size_t)n * 768 + c);
      a0 += b2f(u.x); a1 += b2f(u.y); a2 += b2f(u.z); a3 += b2f(u.w);
    }
  } else {
    for (int n = ns; n < ne; ++n) {
      float4 v = *(const float4*)(feat + (size_t)n * 1024 + c);
      a0 += v.x; a1 += v.y; a2 += v.z; a3 += v.w;
    }
  }
  atomicAdd(&pooled[g * 1024 + c], a0);
  atomicAdd(&pooled[g * 1024 + c + 1], a1);
  atomicAdd(&pooled[g * 1024 + c + 2], a2);
  atomicAdd(&pooled[g * 1024 + c + 3], a3);
}

__global__ __launch_bounds__(256) void k_head(const float* __restrict__ pooled,
                                              const int* __restrict__ gstart,
                                              const float* __restrict__ W1, const float* __restrict__ b1,
                                              const float* __restrict__ W2, const float* __restrict__ b2,
                                              float* __restrict__ out) {
  __shared__ float sp[1024];
  __shared__ float red[256];
  int g = blockIdx.x, t = threadIdx.x;
  float inv = 1.f / fmaxf((float)(gstart[g + 1] - gstart[g]), 1.f);
  for (int i = t; i < 1024; i += 256) sp[i] = pooled[g * 1024 + i] * inv;
  __syncthreads();
  float acc = b1[t];
  for (int k = 0; k < 1024; ++k) acc += sp[k] * W1[k * 256 + t];
  float hc = fmaxf(acc, 0.f);
  red[t] = hc * W2[t];
  __syncthreads();
  for (int s2 = 128; s2 > 0; s2 >>= 1) {
    if (t < s2) red[t] += red[t + s2];
    __syncthreads();
  }
  if (t == 0) out[g] = 1.f / (1.f + expf(-(red[0] + b2[0])));
}

extern "C" void kernel_launch(void* const* d_in, const int* in_sizes, int n_in, void* d_out, int out_size,
                              void* d_ws, size_t ws_size, hipStream_t stream) {
  const float* feat = (const float*)d_in[0];
  const float* W_e = (const float*)d_in[1];
  const float* b_e = (const float*)d_in[2];
  const float* W_ih = (const float*)d_in[3];
  const float* W_hh = (const float*)d_in[4];
  const float* b_ih = (const float*)d_in[5];
  const float* b_hh = (const float*)d_in[6];
  const float* W1 = (const float*)d_in[7];
  const float* b1 = (const float*)d_in[8];
  const float* W2 = (const float*)d_in[9];
  const float* b2 = (const float*)d_in[10];
  const int* src = (const int*)d_in[11];
  const int* dst = (const int*)d_in[12];
  const int* ety = (const int*)d_in[13];
  const int* n2g = (const int*)d_in[14];

  char* p = (char*)d_ws;
  auto alloc = [&](size_t b) { char* r = p; p += (b + 255) & ~(size_t)255; return r; };
  u16* acat = (u16*)alloc((size_t)MPAD * 768 * 2);   // [hbA | ab | hbB]
  u16* ht = (u16*)alloc((size_t)MPAD * 1024 * 2);
  u16* rzb = (u16*)alloc((size_t)MPAD * 512 * 2);
  u16* inb = (u16*)alloc((size_t)MPAD * 256 * 2);
  u16* Wt_e = (u16*)alloc(1024 * 256 * 2);
  u16* Wt_rz_ah = (u16*)alloc(512 * 512 * 2);
  u16* Wt_rz_ha = (u16*)alloc(512 * 512 * 2);
  u16* Wt_in = (u16*)alloc(256 * 256 * 2);
  u16* Wt_hn = (u16*)alloc(256 * 256 * 2);
  float* b_rz = (float*)alloc(512 * 4);
  int* deg = (int*)alloc((size_t)NN * 4);
  int* part = (int*)alloc((size_t)NN * 4);
  int* bsum = (int*)alloc(SCB * 4);
  int* boff = (int*)alloc(257 * 4);
  int* rp = (int*)alloc((size_t)(NN + 1) * 4);
  int* cursor = (int*)alloc((size_t)NN * 4);
  int* goff = (int*)alloc((size_t)NE * 4);
  int* gstart = (int*)alloc((size_t)(NG + 1) * 4);
  float* pooled = (float*)alloc((size_t)NG * 1024 * 4);

  hipMemsetAsync(deg, 0, (size_t)NN * 4, stream);
  hipMemsetAsync(cursor, 0, (size_t)NN * 4, stream);
  hipMemsetAsync(pooled, 0, (size_t)NG * 1024 * 4, stream);

  k_conv_we<<<1024, 256, 0, stream>>>(W_e, Wt_e);
  k_conv_rz<<<1024, 256, 0, stream>>>(W_ih, W_hh, Wt_rz_ah, Wt_rz_ha);
  k_conv_n<<<256, 256, 0, stream>>>(W_ih, Wt_in);
  k_conv_n<<<256, 256, 0, stream>>>(W_hh, Wt_hn);
  k_brz<<<2, 256, 0, stream>>>(b_ih, b_hh, b_rz);
  k_init_h<<<MPAD / 4, 256, 0, stream>>>(feat, acat);
  k_hist<<<(NE + 255) / 256, 256, 0, stream>>>(dst, deg);
  k_scan1<<<SCB, 256, 0, stream>>>(deg, part, bsum);
  k_scan2<<<1, 256, 0, stream>>>(bsum, boff);
  k_scan3<<<SCB + 1, 256, 0, stream>>>(part, boff, rp);
  k_scatter<<<(NE + 255) / 256, 256, 0, stream>>>(src, dst, ety, rp, cursor, goff);
  k_gstart<<<SCB, 256, 0, stream>>>(n2g, gstart);

  for (int s = 0; s < NSTEP; ++s) {
    int hboff = (s & 1) ? 512 : 0;
    int hnewoff = 512 - hboff;
    int rzoff = (s & 1) ? 256 : 0;
    const u16* Wrz = (s & 1) ? Wt_rz_ah : Wt_rz_ha;
    // ht = hb @ W_e (all 4 etypes) + b_e
    k_gemm<0><<<dim3(1024 / BN, MPAD / BM), 256, 0, stream>>>(
        acat + hboff, 768, 256, Wt_e, b_e, ht, 1024, nullptr, nullptr, nullptr, nullptr);
    // ab = segment-sum of gathered messages
    k_aggr<<<MPAD / 4, 256, 0, stream>>>(ht, rp, goff, acat);
    // r,z = sigmoid([ab|hb] @ Wrz + b_rz)
    k_gemm<1><<<dim3(512 / BN, MPAD / BM), 256, 0, stream>>>(
        acat + rzoff, 768, 512, Wrz, b_rz, rzb, 512, nullptr, nullptr, nullptr, nullptr);
    // i_n = ab @ W_ih[:,512:] + b_ih[512:]
    k_gemm<0><<<dim3(256 / BN, MPAD / BM), 256, 0, stream>>>(
        acat + 256, 768, 256, Wt_in, b_ih + 512, inb, 256, nullptr, nullptr, nullptr, nullptr);
    // h_n GEMM + fused GRU combine -> hnew
    k_gemm<2><<<dim3(256 / BN, MPAD / BM), 256, 0, stream>>>(
        acat + hboff, 768, 256, Wt_hn, b_hh + 512, nullptr, 0, rzb, inb, acat + hboff,
        acat + hnewoff);
  }

  // after step 7 (odd), final h is in hbA (offset 0)
  k_pool<<<dim3(NG, PCH), 256, 0, stream>>>(acat, feat, gstart, pooled);
  k_head<<<NG, 256, 0, stream>>>(pooled, gstart, W1, b1, W2, b2, (float*)d_out);
}